// Round 8
// baseline (320.784 us; speedup 1.0000x reference)
//
#include <hip/hip_runtime.h>

// FeatureRefine, MI355X/gfx950 — round 13.
// R12 post-mortem: 2-deep pipeline raised VGPR 28->48 and per-wave MLP, but
// launch_bounds(256,4) capped occupancy at 43% -> 58.5us (R8 simple+occ8:
// 52us). Compiler chose 48 VGPR <= 64 = the 8-waves/SIMD threshold, so the
// pipeline fits full occupancy. Single change this round:
//  fr_refine: __launch_bounds__(256, 8)  (pipeline + 8 blocks/CU).
// Transpose kept byte-identical: non-refine time has been invariant ~106us
// across ALL transpose variants; with refine at ~40us the transpose should
// finally surface in top-5 and yield counters.

#define N_ 4
#define C_ 256
#define H_ 128
#define W_ 128
#define HW_ (H_ * W_)
#define SCALE 0.125f

typedef unsigned int uint32;
typedef float f32x2 __attribute__((ext_vector_type(2)));

__device__ __forceinline__ uint32 f2bf(float f) {
    uint32 u = __float_as_uint(f);
    u = (u + 0x7FFF + ((u >> 16) & 1)) >> 16;   // RNE
    return u;
}
__device__ __forceinline__ float blo(uint32 u) { return __uint_as_float(u << 16); }
__device__ __forceinline__ float bhi(uint32 u) { return __uint_as_float(u & 0xFFFF0000u); }

// ---------- Pass 0: NCHW fp32 -> NHWC bf16 (packed ch-pairs) + fused geo ----------
// Tile 256 hw x 128 ch (one c-half). 1024 thr / 16 waves; 4 cpairs per wave.
// LDS [64 cpair][256 hw + pad] = 66.5 KB -> 2 blocks/CU.
__global__ __launch_bounds__(1024, 8) void nchw2nhwc_geo(const float* __restrict__ in,
                                                         const float* __restrict__ bb,
                                                         uint32* __restrict__ outU,
                                                         uint32* __restrict__ geoG)
{
    __shared__ uint32 tile[64 * 260];
    const int t   = threadIdx.x;
    const int l   = t & 63;
    const int g   = t >> 6;               // wave 0..15
    const int hw0 = blockIdx.x * 256;
    const int ch  = blockIdx.y;           // c-half 0/1
    const int n   = blockIdx.z;

    if (ch == 0 && t < 256) {             // fused geo for this block's pixels
        const int px = n * HW_ + hw0 + t;
        const float* b = bb + (size_t)px * 5;
        const float cx = b[0], cy = b[1], bw = b[2], bh = b[3], th = b[4];
        const float st = sinf(th), ct = cosf(th);
        const float vx = bw * ct * 0.5f, vy = bw * st * 0.5f;
        const float wx = -bh * st * 0.5f, wy = bh * ct * 0.5f;
        const float pxs[5] = {cx, cx + vx + wx, cx - vx + wx, cx - vx - wx, cx + vx - wx};
        const float pys[5] = {cy, cy + vy + wy, cy - vy + wy, cy - vy - wy, cy + vy - wy};
        uint32* gw = geoG + (size_t)px * 40;   // 160B: 5 pts x 4 corners x 8B
#pragma unroll
        for (int p = 0; p < 5; ++p) {
            float x = pxs[p] * SCALE;
            float y = pys[p] * SCALE;
            const bool valid = (y >= -1.0f) && (y <= (float)H_) &&
                               (x >= -1.0f) && (x <= (float)W_);
            y = fmaxf(y, 0.0f);
            x = fmaxf(x, 0.0f);
            int yl = min((int)y, H_ - 1);
            int xl = min((int)x, W_ - 1);
            if (yl >= H_ - 1) y = (float)yl;   // mmcv border snap: ly = 0
            if (xl >= W_ - 1) x = (float)xl;   // lx = 0
            const int yh = min(yl + 1, H_ - 1);
            const float ly = y - (float)yl, lx = x - (float)xl;
            const float hy = 1.0f - ly,     hx = 1.0f - lx;
            const int xa = min(xl, W_ - 2);
            float wA, wB;
            if (xl < W_ - 1) { wA = hx; wB = lx; }
            else             { wA = 0.0f; wB = 1.0f; }
            const float v = valid ? 1.0f : 0.0f;
            const int pix0 = yl * W_ + xa;
            const int pix1 = yh * W_ + xa;
            // corner k: 0=(yl,xa) 1=(yl,xa+1) 2=(yh,xa) 3=(yh,xa+1)
            *(uint4*)&gw[p * 8]     = make_uint4((uint32)(pix0 * 512),
                                                 __float_as_uint(v * hy * wA),
                                                 (uint32)((pix0 + 1) * 512),
                                                 __float_as_uint(v * hy * wB));
            *(uint4*)&gw[p * 8 + 4] = make_uint4((uint32)(pix1 * 512),
                                                 __float_as_uint(v * ly * wA),
                                                 (uint32)((pix1 + 1) * 512),
                                                 __float_as_uint(v * ly * wB));
        }
    }

    // channels of this half: ch*128 + 2cp, 2cp+1 for cp = 0..63
    const float* base = in + (size_t)n * C_ * HW_ + (size_t)(ch * 128) * HW_ + hw0 + 4 * l;
    float4 v0[4], v1[4];
#pragma unroll
    for (int r = 0; r < 4; ++r) {
        const int cp = g * 4 + r;
        v0[r] = *(const float4*)(base + (size_t)(2 * cp) * HW_);
        v1[r] = *(const float4*)(base + (size_t)(2 * cp + 1) * HW_);
    }
#pragma unroll
    for (int r = 0; r < 4; ++r) {
        const int cp = g * 4 + r;
        uint4 u;
        u.x = f2bf(v0[r].x) | (f2bf(v1[r].x) << 16);
        u.y = f2bf(v0[r].y) | (f2bf(v1[r].y) << 16);
        u.z = f2bf(v0[r].z) | (f2bf(v1[r].z) << 16);
        u.w = f2bf(v0[r].w) | (f2bf(v1[r].w) << 16);
        *(uint4*)&tile[cp * 260 + 4 * l] = u;   // b128, conflict-free
    }
    __syncthreads();
    // epilogue: 16B/lane uint4 stores. Per iter: 64 px, 16 thr/px.
    uint32* dst = outU + ((size_t)n * HW_ + hw0) * 128 + ch * 64;
#pragma unroll
    for (int it = 0; it < 4; ++it) {
        const int px  = it * 64 + (t >> 4);   // 0..255
        const int cp0 = (t & 15) * 4;
        uint4 v;
        v.x = tile[(cp0 + 0) * 260 + px];
        v.y = tile[(cp0 + 1) * 260 + px];
        v.z = tile[(cp0 + 2) * 260 + px];
        v.w = tile[(cp0 + 3) * 260 + px];
        *(uint4*)&dst[(size_t)px * 128 + cp0] = v;
    }
}

// ---------- Pass 1: refine v8 — corner-keyed geo, 2-deep pipeline, occ 8 ----------
// Block: 256 thr, 32 px x 128 ch (c-half from XCD id). Per point, ONE
// 64-lane x 16B load covers all 4 bilinear corners; lane group l>>4 is the
// corner id. Pipeline: iter p issues geo(p+2) + gathers(p+1), computes p.
// launch_bounds(256,8): VGPR cap 64 (compiler used 48 at cap 128) -> 8
// blocks/CU, 100% occupancy target WITH the pipeline's MLP.
__global__ __launch_bounds__(256, 8) void fr_refine(const uint32* __restrict__ nhwcU,
                                                    const uint32* __restrict__ geoG,
                                                    float* __restrict__ out)
{
    __shared__ float tile[32 * 128];      // [px][c] fp32, XOR-swizzled, 16 KB
    const int t  = threadIdx.x;
    const int l  = t & 63;
    const int wv = __builtin_amdgcn_readfirstlane(t >> 6);
    const int bx = blockIdx.x;            // [0, 4096)
    // XCD (bx&7) = (batch, c-half): per-XCD gather set = 4MB = one L2.
    const int xcd = bx & 7;
    const int n   = xcd >> 1;
    const int ch  = xcd & 1;
    const int s   = bx >> 3;              // [0, 512) = 128 h x 4 w-tiles
    const int h   = s >> 2;
    const int w0  = (s & 3) * 32;

    const int k8   = (l >> 4) << 3;       // corner id * 8 bytes
    const int slot = (l & 15) << 4;       // 16B slot within 256B segment
    const int hwb  = h * W_ + w0 + wv * 8;
    const char* gbase = (const char*)geoG + (size_t)(n * HW_ + hwb) * 160;
    const char* plane = (const char*)(nhwcU + (size_t)n * HW_ * 128) + (ch << 8);
    const bool idlane = (l < 16);

    uint2 owA[5], owB[5], owC[5];
    uint4 rA[5], rB[5];
    uint4 ridA, ridB;

    // ---- prologue: geo(0), geo(1), gather(0) ----
#pragma unroll
    for (int q = 0; q < 5; ++q) owA[q] = *(const uint2*)(gbase + q * 32 + k8);
#pragma unroll
    for (int q = 0; q < 5; ++q) owB[q] = *(const uint2*)(gbase + 160 + q * 32 + k8);
    ridA = make_uint4(0u, 0u, 0u, 0u);
    if (idlane) ridA = *(const uint4*)(plane + (size_t)hwb * 512 + slot);
#pragma unroll
    for (int q = 0; q < 5; ++q) rA[q] = *(const uint4*)(plane + owA[q].x + slot);
    __builtin_amdgcn_sched_barrier(0);

#pragma unroll
    for (int p = 0; p < 8; ++p) {
        // stage 1: issue geo(p+2)
        if (p + 2 < 8) {
#pragma unroll
            for (int q = 0; q < 5; ++q)
                owC[q] = *(const uint2*)(gbase + (p + 2) * 160 + q * 32 + k8);
        }
        // stage 2: issue gathers(p+1) from owB (loaded one iter ago)
        if (p + 1 < 8) {
            ridB = make_uint4(0u, 0u, 0u, 0u);
            if (idlane) ridB = *(const uint4*)(plane + (size_t)(hwb + p + 1) * 512 + slot);
#pragma unroll
            for (int q = 0; q < 5; ++q)
                rB[q] = *(const uint4*)(plane + owB[q].x + slot);
        }
        __builtin_amdgcn_sched_barrier(0);

        // stage 3: compute p from rA / owA weights
        f32x2 acc0, acc1, acc2, acc3;
        acc0.x = blo(ridA.x); acc0.y = bhi(ridA.x);
        acc1.x = blo(ridA.y); acc1.y = bhi(ridA.y);
        acc2.x = blo(ridA.z); acc2.y = bhi(ridA.z);
        acc3.x = blo(ridA.w); acc3.y = bhi(ridA.w);
#pragma unroll
        for (int q = 0; q < 5; ++q) {
            const float w = __uint_as_float(owA[q].y);
            f32x2 w2; w2.x = w; w2.y = w;
            f32x2 u;
            u.x = blo(rA[q].x); u.y = bhi(rA[q].x); acc0 += u * w2;
            u.x = blo(rA[q].y); u.y = bhi(rA[q].y); acc1 += u * w2;
            u.x = blo(rA[q].z); u.y = bhi(rA[q].z); acc2 += u * w2;
            u.x = blo(rA[q].w); u.y = bhi(rA[q].w); acc3 += u * w2;
        }
        float a[8] = {acc0.x, acc0.y, acc1.x, acc1.y,
                      acc2.x, acc2.y, acc3.x, acc3.y};
#pragma unroll
        for (int k = 0; k < 8; ++k) {
            a[k] += __shfl_xor(a[k], 16, 64);
            a[k] += __shfl_xor(a[k], 32, 64);
        }
        if (idlane) {                      // lanes 0-15 hold ch 8l..8l+7
            const int px  = wv * 8 + p;
            const int swz = (px & 7) << 2;
            float* base = &tile[px * 128];
            *(float4*)&base[(l * 8) ^ swz]     = make_float4(a[0], a[1], a[2], a[3]);
            *(float4*)&base[(l * 8 + 4) ^ swz] = make_float4(a[4], a[5], a[6], a[7]);
        }

        // rotate pipeline registers (renamed by full unroll)
#pragma unroll
        for (int q = 0; q < 5; ++q) { owA[q] = owB[q]; owB[q] = owC[q]; rA[q] = rB[q]; }
        ridA = ridB;
    }
    __syncthreads();
    // epilogue: [32px][128c] -> NCHW; swizzled read is 4-way (~free)
    const size_t obase = (size_t)n * C_ * HW_ + (size_t)(ch * 128) * HW_ + h * W_ + w0;
#pragma unroll
    for (int it = 0; it < 16; ++it) {
        const int flat = it * 256 + t;
        const int px = flat & 31;
        const int c  = flat >> 5;          // 0..127
        out[obase + (size_t)c * HW_ + px] = tile[px * 128 + (c ^ ((px & 7) << 2))];
    }
}

// ---------- Fallback (round-1 kernel) if ws too small ----------
__global__ __launch_bounds__(256) void fr_kernel(
    const float* __restrict__ feat,
    const float* __restrict__ bb,
    float* __restrict__ out)
{
    const int lane = threadIdx.x & 63;
    const int wave = threadIdx.x >> 6;
    const int tile = blockIdx.x;
    const int wt   = tile & 1;
    const int h    = (tile >> 1) & (H_ - 1);
    const int n    = tile >> 8;
    const int w    = wt * 64 + lane;
    const int cb   = blockIdx.y;

    const float* b = bb + (size_t)((n * H_ + h) * W_ + w) * 5;
    const float cx = b[0], cy = b[1], bw = b[2], bh = b[3], th = b[4];
    const float st = sinf(th), ct = cosf(th);
    const float vx = bw * ct * 0.5f, vy = bw * st * 0.5f;
    const float wx = -bh * st * 0.5f, wy = bh * ct * 0.5f;
    const float pxs[5] = {cx, cx + vx + wx, cx - vx + wx, cx - vx - wx, cx + vx - wx};
    const float pys[5] = {cy, cy + vy + wy, cy - vy + wy, cy - vy - wy, cy + vy - wy};

    int   off0[5], off1[5];
    float wgt[20];
#pragma unroll
    for (int p = 0; p < 5; ++p) {
        float x = pxs[p] * SCALE;
        float y = pys[p] * SCALE;
        const bool valid = (y >= -1.0f) && (y <= (float)H_) &&
                           (x >= -1.0f) && (x <= (float)W_);
        y = fmaxf(y, 0.0f);
        x = fmaxf(x, 0.0f);
        int yl = min((int)y, H_ - 1);
        int xl = min((int)x, W_ - 1);
        if (yl >= H_ - 1) y = (float)yl;
        if (xl >= W_ - 1) x = (float)xl;
        const int yh = min(yl + 1, H_ - 1);
        const float ly = y - (float)yl, lx = x - (float)xl;
        const float hy = 1.0f - ly,     hx = 1.0f - lx;
        const int xa = min(xl, W_ - 2);
        float wA, wB;
        if (xl < W_ - 1) { wA = hx; wB = lx; }
        else             { wA = 0.0f; wB = 1.0f; }
        const float v = valid ? 1.0f : 0.0f;
        off0[p] = yl * W_ + xa;
        off1[p] = yh * W_ + xa;
        wgt[p * 4 + 0] = v * hy * wA;
        wgt[p * 4 + 1] = v * hy * wB;
        wgt[p * 4 + 2] = v * ly * wA;
        wgt[p * 4 + 3] = v * ly * wB;
    }

    const int hw = h * W_ + w;
    const size_t planeBase = ((size_t)n * C_ + cb * 64 + wave * 16) * HW_;
    const float* fp = feat + planeBase;
    float*       op = out  + planeBase;
    for (int it = 0; it < 16; ++it) {
        float acc = fp[hw];
#pragma unroll
        for (int p = 0; p < 5; ++p) {
            acc += wgt[p * 4 + 0] * fp[off0[p]]
                 + wgt[p * 4 + 1] * fp[off0[p] + 1]
                 + wgt[p * 4 + 2] * fp[off1[p]]
                 + wgt[p * 4 + 3] * fp[off1[p] + 1];
        }
        op[hw] = acc;
        fp += HW_;
        op += HW_;
    }
}

extern "C" void kernel_launch(void* const* d_in, const int* in_sizes, int n_in,
                              void* d_out, int out_size, void* d_ws, size_t ws_size,
                              hipStream_t stream) {
    const float* feat = (const float*)d_in[0];   // [N,C,H,W] fp32
    const float* bbox = (const float*)d_in[1];   // [N,H,W,5] fp32
    float* out = (float*)d_out;

    const size_t nhwcBytes = (size_t)N_ * HW_ * C_ * 2;        // 32 MB bf16
    const size_t geoBytes  = (size_t)N_ * HW_ * 160;           // 10.5 MB
    if (ws_size >= nhwcBytes + geoBytes) {
        uint32* nhwcU = (uint32*)d_ws;
        uint32* geoG  = (uint32*)((char*)d_ws + nhwcBytes);
        nchw2nhwc_geo<<<dim3(HW_ / 256, 2, N_), dim3(1024), 0, stream>>>(feat, bbox, nhwcU, geoG);
        fr_refine<<<dim3(N_ * H_ * (W_ / 32) * 2), dim3(256), 0, stream>>>(nhwcU, geoG, out);
    } else {
        dim3 grid(N_ * H_ * (W_ / 64), C_ / 64, 1);
        fr_kernel<<<grid, dim3(256), 0, stream>>>(feat, bbox, out);
    }
}

// Round 9
// 221.232 us; speedup vs baseline: 1.4500x; 1.4500x over previous
//
#include <hip/hip_runtime.h>

// FeatureRefine, MI355X/gfx950 — round 14.
// R13 post-mortem: launch_bounds(256,8) (VGPR cap 64) vs pipeline's 48-VGPR
// live state -> allocator spilled to scratch: VGPR=32 reported, WRITE_SIZE
// 65->397MB/dispatch, refine 204us. Lesson: bound must leave headroom over
// the pipeline's live state.
// Single change vs R12 (last clean measurement, 58.5us @ 43% occ):
//  fr_refine: __launch_bounds__(256, 6)  -> VGPR cap ~84 (2x headroom over
//  48 needed), occupancy target 75%. Pipeline + waves, no spill.
// Transpose byte-identical (4 variants all left non-refine time at ~107us).

#define N_ 4
#define C_ 256
#define H_ 128
#define W_ 128
#define HW_ (H_ * W_)
#define SCALE 0.125f

typedef unsigned int uint32;
typedef float f32x2 __attribute__((ext_vector_type(2)));

__device__ __forceinline__ uint32 f2bf(float f) {
    uint32 u = __float_as_uint(f);
    u = (u + 0x7FFF + ((u >> 16) & 1)) >> 16;   // RNE
    return u;
}
__device__ __forceinline__ float blo(uint32 u) { return __uint_as_float(u << 16); }
__device__ __forceinline__ float bhi(uint32 u) { return __uint_as_float(u & 0xFFFF0000u); }

// ---------- Pass 0: NCHW fp32 -> NHWC bf16 (packed ch-pairs) + fused geo ----------
// Tile 256 hw x 128 ch (one c-half). 1024 thr / 16 waves; 4 cpairs per wave.
// LDS [64 cpair][256 hw + pad] = 66.5 KB -> 2 blocks/CU.
__global__ __launch_bounds__(1024, 8) void nchw2nhwc_geo(const float* __restrict__ in,
                                                         const float* __restrict__ bb,
                                                         uint32* __restrict__ outU,
                                                         uint32* __restrict__ geoG)
{
    __shared__ uint32 tile[64 * 260];
    const int t   = threadIdx.x;
    const int l   = t & 63;
    const int g   = t >> 6;               // wave 0..15
    const int hw0 = blockIdx.x * 256;
    const int ch  = blockIdx.y;           // c-half 0/1
    const int n   = blockIdx.z;

    if (ch == 0 && t < 256) {             // fused geo for this block's pixels
        const int px = n * HW_ + hw0 + t;
        const float* b = bb + (size_t)px * 5;
        const float cx = b[0], cy = b[1], bw = b[2], bh = b[3], th = b[4];
        const float st = sinf(th), ct = cosf(th);
        const float vx = bw * ct * 0.5f, vy = bw * st * 0.5f;
        const float wx = -bh * st * 0.5f, wy = bh * ct * 0.5f;
        const float pxs[5] = {cx, cx + vx + wx, cx - vx + wx, cx - vx - wx, cx + vx - wx};
        const float pys[5] = {cy, cy + vy + wy, cy - vy + wy, cy - vy - wy, cy + vy - wy};
        uint32* gw = geoG + (size_t)px * 40;   // 160B: 5 pts x 4 corners x 8B
#pragma unroll
        for (int p = 0; p < 5; ++p) {
            float x = pxs[p] * SCALE;
            float y = pys[p] * SCALE;
            const bool valid = (y >= -1.0f) && (y <= (float)H_) &&
                               (x >= -1.0f) && (x <= (float)W_);
            y = fmaxf(y, 0.0f);
            x = fmaxf(x, 0.0f);
            int yl = min((int)y, H_ - 1);
            int xl = min((int)x, W_ - 1);
            if (yl >= H_ - 1) y = (float)yl;   // mmcv border snap: ly = 0
            if (xl >= W_ - 1) x = (float)xl;   // lx = 0
            const int yh = min(yl + 1, H_ - 1);
            const float ly = y - (float)yl, lx = x - (float)xl;
            const float hy = 1.0f - ly,     hx = 1.0f - lx;
            const int xa = min(xl, W_ - 2);
            float wA, wB;
            if (xl < W_ - 1) { wA = hx; wB = lx; }
            else             { wA = 0.0f; wB = 1.0f; }
            const float v = valid ? 1.0f : 0.0f;
            const int pix0 = yl * W_ + xa;
            const int pix1 = yh * W_ + xa;
            // corner k: 0=(yl,xa) 1=(yl,xa+1) 2=(yh,xa) 3=(yh,xa+1)
            *(uint4*)&gw[p * 8]     = make_uint4((uint32)(pix0 * 512),
                                                 __float_as_uint(v * hy * wA),
                                                 (uint32)((pix0 + 1) * 512),
                                                 __float_as_uint(v * hy * wB));
            *(uint4*)&gw[p * 8 + 4] = make_uint4((uint32)(pix1 * 512),
                                                 __float_as_uint(v * ly * wA),
                                                 (uint32)((pix1 + 1) * 512),
                                                 __float_as_uint(v * ly * wB));
        }
    }

    // channels of this half: ch*128 + 2cp, 2cp+1 for cp = 0..63
    const float* base = in + (size_t)n * C_ * HW_ + (size_t)(ch * 128) * HW_ + hw0 + 4 * l;
    float4 v0[4], v1[4];
#pragma unroll
    for (int r = 0; r < 4; ++r) {
        const int cp = g * 4 + r;
        v0[r] = *(const float4*)(base + (size_t)(2 * cp) * HW_);
        v1[r] = *(const float4*)(base + (size_t)(2 * cp + 1) * HW_);
    }
#pragma unroll
    for (int r = 0; r < 4; ++r) {
        const int cp = g * 4 + r;
        uint4 u;
        u.x = f2bf(v0[r].x) | (f2bf(v1[r].x) << 16);
        u.y = f2bf(v0[r].y) | (f2bf(v1[r].y) << 16);
        u.z = f2bf(v0[r].z) | (f2bf(v1[r].z) << 16);
        u.w = f2bf(v0[r].w) | (f2bf(v1[r].w) << 16);
        *(uint4*)&tile[cp * 260 + 4 * l] = u;   // b128, conflict-free
    }
    __syncthreads();
    // epilogue: 16B/lane uint4 stores. Per iter: 64 px, 16 thr/px.
    uint32* dst = outU + ((size_t)n * HW_ + hw0) * 128 + ch * 64;
#pragma unroll
    for (int it = 0; it < 4; ++it) {
        const int px  = it * 64 + (t >> 4);   // 0..255
        const int cp0 = (t & 15) * 4;
        uint4 v;
        v.x = tile[(cp0 + 0) * 260 + px];
        v.y = tile[(cp0 + 1) * 260 + px];
        v.z = tile[(cp0 + 2) * 260 + px];
        v.w = tile[(cp0 + 3) * 260 + px];
        *(uint4*)&dst[(size_t)px * 128 + cp0] = v;
    }
}

// ---------- Pass 1: refine v9 — corner-keyed geo, 2-deep pipeline, occ 6 ----------
// Block: 256 thr, 32 px x 128 ch (c-half from XCD id). Per point, ONE
// 64-lane x 16B load covers all 4 bilinear corners; lane group l>>4 is the
// corner id. Pipeline: iter p issues geo(p+2) + gathers(p+1), computes p.
// launch_bounds(256,6): VGPR cap ~84 >> 48 live state (R13: cap 64 spilled).
__global__ __launch_bounds__(256, 6) void fr_refine(const uint32* __restrict__ nhwcU,
                                                    const uint32* __restrict__ geoG,
                                                    float* __restrict__ out)
{
    __shared__ float tile[32 * 128];      // [px][c] fp32, XOR-swizzled, 16 KB
    const int t  = threadIdx.x;
    const int l  = t & 63;
    const int wv = __builtin_amdgcn_readfirstlane(t >> 6);
    const int bx = blockIdx.x;            // [0, 4096)
    // XCD (bx&7) = (batch, c-half): per-XCD gather set = 4MB = one L2.
    const int xcd = bx & 7;
    const int n   = xcd >> 1;
    const int ch  = xcd & 1;
    const int s   = bx >> 3;              // [0, 512) = 128 h x 4 w-tiles
    const int h   = s >> 2;
    const int w0  = (s & 3) * 32;

    const int k8   = (l >> 4) << 3;       // corner id * 8 bytes
    const int slot = (l & 15) << 4;       // 16B slot within 256B segment
    const int hwb  = h * W_ + w0 + wv * 8;
    const char* gbase = (const char*)geoG + (size_t)(n * HW_ + hwb) * 160;
    const char* plane = (const char*)(nhwcU + (size_t)n * HW_ * 128) + (ch << 8);
    const bool idlane = (l < 16);

    uint2 owA[5], owB[5], owC[5];
    uint4 rA[5], rB[5];
    uint4 ridA, ridB;

    // ---- prologue: geo(0), geo(1), gather(0) ----
#pragma unroll
    for (int q = 0; q < 5; ++q) owA[q] = *(const uint2*)(gbase + q * 32 + k8);
#pragma unroll
    for (int q = 0; q < 5; ++q) owB[q] = *(const uint2*)(gbase + 160 + q * 32 + k8);
    ridA = make_uint4(0u, 0u, 0u, 0u);
    if (idlane) ridA = *(const uint4*)(plane + (size_t)hwb * 512 + slot);
#pragma unroll
    for (int q = 0; q < 5; ++q) rA[q] = *(const uint4*)(plane + owA[q].x + slot);
    __builtin_amdgcn_sched_barrier(0);

#pragma unroll
    for (int p = 0; p < 8; ++p) {
        // stage 1: issue geo(p+2)
        if (p + 2 < 8) {
#pragma unroll
            for (int q = 0; q < 5; ++q)
                owC[q] = *(const uint2*)(gbase + (p + 2) * 160 + q * 32 + k8);
        }
        // stage 2: issue gathers(p+1) from owB (loaded one iter ago)
        if (p + 1 < 8) {
            ridB = make_uint4(0u, 0u, 0u, 0u);
            if (idlane) ridB = *(const uint4*)(plane + (size_t)(hwb + p + 1) * 512 + slot);
#pragma unroll
            for (int q = 0; q < 5; ++q)
                rB[q] = *(const uint4*)(plane + owB[q].x + slot);
        }
        __builtin_amdgcn_sched_barrier(0);

        // stage 3: compute p from rA / owA weights
        f32x2 acc0, acc1, acc2, acc3;
        acc0.x = blo(ridA.x); acc0.y = bhi(ridA.x);
        acc1.x = blo(ridA.y); acc1.y = bhi(ridA.y);
        acc2.x = blo(ridA.z); acc2.y = bhi(ridA.z);
        acc3.x = blo(ridA.w); acc3.y = bhi(ridA.w);
#pragma unroll
        for (int q = 0; q < 5; ++q) {
            const float w = __uint_as_float(owA[q].y);
            f32x2 w2; w2.x = w; w2.y = w;
            f32x2 u;
            u.x = blo(rA[q].x); u.y = bhi(rA[q].x); acc0 += u * w2;
            u.x = blo(rA[q].y); u.y = bhi(rA[q].y); acc1 += u * w2;
            u.x = blo(rA[q].z); u.y = bhi(rA[q].z); acc2 += u * w2;
            u.x = blo(rA[q].w); u.y = bhi(rA[q].w); acc3 += u * w2;
        }
        float a[8] = {acc0.x, acc0.y, acc1.x, acc1.y,
                      acc2.x, acc2.y, acc3.x, acc3.y};
#pragma unroll
        for (int k = 0; k < 8; ++k) {
            a[k] += __shfl_xor(a[k], 16, 64);
            a[k] += __shfl_xor(a[k], 32, 64);
        }
        if (idlane) {                      // lanes 0-15 hold ch 8l..8l+7
            const int px  = wv * 8 + p;
            const int swz = (px & 7) << 2;
            float* base = &tile[px * 128];
            *(float4*)&base[(l * 8) ^ swz]     = make_float4(a[0], a[1], a[2], a[3]);
            *(float4*)&base[(l * 8 + 4) ^ swz] = make_float4(a[4], a[5], a[6], a[7]);
        }

        // rotate pipeline registers (renamed by full unroll)
#pragma unroll
        for (int q = 0; q < 5; ++q) { owA[q] = owB[q]; owB[q] = owC[q]; rA[q] = rB[q]; }
        ridA = ridB;
    }
    __syncthreads();
    // epilogue: [32px][128c] -> NCHW; swizzled read is 4-way (~free)
    const size_t obase = (size_t)n * C_ * HW_ + (size_t)(ch * 128) * HW_ + h * W_ + w0;
#pragma unroll
    for (int it = 0; it < 16; ++it) {
        const int flat = it * 256 + t;
        const int px = flat & 31;
        const int c  = flat >> 5;          // 0..127
        out[obase + (size_t)c * HW_ + px] = tile[px * 128 + (c ^ ((px & 7) << 2))];
    }
}

// ---------- Fallback (round-1 kernel) if ws too small ----------
__global__ __launch_bounds__(256) void fr_kernel(
    const float* __restrict__ feat,
    const float* __restrict__ bb,
    float* __restrict__ out)
{
    const int lane = threadIdx.x & 63;
    const int wave = threadIdx.x >> 6;
    const int tile = blockIdx.x;
    const int wt   = tile & 1;
    const int h    = (tile >> 1) & (H_ - 1);
    const int n    = tile >> 8;
    const int w    = wt * 64 + lane;
    const int cb   = blockIdx.y;

    const float* b = bb + (size_t)((n * H_ + h) * W_ + w) * 5;
    const float cx = b[0], cy = b[1], bw = b[2], bh = b[3], th = b[4];
    const float st = sinf(th), ct = cosf(th);
    const float vx = bw * ct * 0.5f, vy = bw * st * 0.5f;
    const float wx = -bh * st * 0.5f, wy = bh * ct * 0.5f;
    const float pxs[5] = {cx, cx + vx + wx, cx - vx + wx, cx - vx - wx, cx + vx - wx};
    const float pys[5] = {cy, cy + vy + wy, cy - vy + wy, cy - vy - wy, cy + vy - wy};

    int   off0[5], off1[5];
    float wgt[20];
#pragma unroll
    for (int p = 0; p < 5; ++p) {
        float x = pxs[p] * SCALE;
        float y = pys[p] * SCALE;
        const bool valid = (y >= -1.0f) && (y <= (float)H_) &&
                           (x >= -1.0f) && (x <= (float)W_);
        y = fmaxf(y, 0.0f);
        x = fmaxf(x, 0.0f);
        int yl = min((int)y, H_ - 1);
        int xl = min((int)x, W_ - 1);
        if (yl >= H_ - 1) y = (float)yl;
        if (xl >= W_ - 1) x = (float)xl;
        const int yh = min(yl + 1, H_ - 1);
        const float ly = y - (float)yl, lx = x - (float)xl;
        const float hy = 1.0f - ly,     hx = 1.0f - lx;
        const int xa = min(xl, W_ - 2);
        float wA, wB;
        if (xl < W_ - 1) { wA = hx; wB = lx; }
        else             { wA = 0.0f; wB = 1.0f; }
        const float v = valid ? 1.0f : 0.0f;
        off0[p] = yl * W_ + xa;
        off1[p] = yh * W_ + xa;
        wgt[p * 4 + 0] = v * hy * wA;
        wgt[p * 4 + 1] = v * hy * wB;
        wgt[p * 4 + 2] = v * ly * wA;
        wgt[p * 4 + 3] = v * ly * wB;
    }

    const int hw = h * W_ + w;
    const size_t planeBase = ((size_t)n * C_ + cb * 64 + wave * 16) * HW_;
    const float* fp = feat + planeBase;
    float*       op = out  + planeBase;
    for (int it = 0; it < 16; ++it) {
        float acc = fp[hw];
#pragma unroll
        for (int p = 0; p < 5; ++p) {
            acc += wgt[p * 4 + 0] * fp[off0[p]]
                 + wgt[p * 4 + 1] * fp[off0[p] + 1]
                 + wgt[p * 4 + 2] * fp[off1[p]]
                 + wgt[p * 4 + 3] * fp[off1[p] + 1];
        }
        op[hw] = acc;
        fp += HW_;
        op += HW_;
    }
}

extern "C" void kernel_launch(void* const* d_in, const int* in_sizes, int n_in,
                              void* d_out, int out_size, void* d_ws, size_t ws_size,
                              hipStream_t stream) {
    const float* feat = (const float*)d_in[0];   // [N,C,H,W] fp32
    const float* bbox = (const float*)d_in[1];   // [N,H,W,5] fp32
    float* out = (float*)d_out;

    const size_t nhwcBytes = (size_t)N_ * HW_ * C_ * 2;        // 32 MB bf16
    const size_t geoBytes  = (size_t)N_ * HW_ * 160;           // 10.5 MB
    if (ws_size >= nhwcBytes + geoBytes) {
        uint32* nhwcU = (uint32*)d_ws;
        uint32* geoG  = (uint32*)((char*)d_ws + nhwcBytes);
        nchw2nhwc_geo<<<dim3(HW_ / 256, 2, N_), dim3(1024), 0, stream>>>(feat, bbox, nhwcU, geoG);
        fr_refine<<<dim3(N_ * H_ * (W_ / 32) * 2), dim3(256), 0, stream>>>(nhwcU, geoG, out);
    } else {
        dim3 grid(N_ * H_ * (W_ / 64), C_ / 64, 1);
        fr_kernel<<<grid, dim3(256), 0, stream>>>(feat, bbox, out);
    }
}